// Round 19
// baseline (57.956 us; speedup 1.0000x reference)
//
#include <hip/hip_runtime.h>
#include <hip/hip_bf16.h>

typedef __attribute__((ext_vector_type(8))) short short8v;
typedef __attribute__((ext_vector_type(4))) float float4v;

#define BATCH 8192
#define NVERT 778
#define NJOINT 16
#define NPOSE 135
#define KEXT  160          // 135 pose + 10 beta + 1 const + 14 zero
#define NVT   52           // vertex 16-tiles (52*16 = 832; 49 valid)

// workspace byte offsets (all 16B aligned)
#define WSB_JS    0u
#define WSB_PFX   4096u                        // bf16 [8192][160]
#define WSB_A     (WSB_PFX  + 2621440u)        // (unused, kept for layout)
#define WSB_PTXF  (WSB_A    + 6291456u)        // bf16 [52][3][5][64][8]  h-B frags
#define WSB_WF    (WSB_PTXF + 798720u)         // bf16 [52][64][8]        T-B frags (W)
#define WSB_ATF   (WSB_WF   + 53248u)          // bf16 [512][12][32][8]   T-A frags

// ---------------------------------------------------------------------------
// Kernel A (merged): blocks [0,132) fold J_reg into S,V; blocks [132,340)
// build fragment-order PtxF / WF.   (verbatim from passing r16)
// ---------------------------------------------------------------------------
__global__ __launch_bounds__(256) void prep_kernel(
    const float* __restrict__ S, const float* __restrict__ V,
    const float* __restrict__ J_reg, const float* __restrict__ P,
    const float* __restrict__ W,
    float* __restrict__ wsJS, __hip_bfloat16* __restrict__ PtxF,
    __hip_bfloat16* __restrict__ WF)
{
    if (blockIdx.x < 132) {
        int o = blockIdx.x * 4 + (threadIdx.x >> 6);
        int lane = threadIdx.x & 63;
        float s = 0.f;
        if (o < 480) {
            int j = o / 30, k = (o / 10) % 3, l = o % 10;
            for (int v = lane; v < NVERT; v += 64)
                s += J_reg[j * NVERT + v] * S[v * 30 + k * 10 + l];
        } else if (o < 528) {
            int o2 = o - 480;
            int j = o2 / 3, k = o2 % 3;
            for (int v = lane; v < NVERT; v += 64)
                s += J_reg[j * NVERT + v] * V[v * 3 + k];
        }
#pragma unroll
        for (int m = 32; m >= 1; m >>= 1) s += __shfl_xor(s, m, 64);
        if (lane == 0 && o < 528) wsJS[o] = s;
        return;
    }

    int idx = (blockIdx.x - 132) * 256 + threadIdx.x;
    if (idx < NVT * 3 * 5 * 64) {
        int vt = idx / 960;
        int rem = idx % 960;
        int k = rem / 320;
        int rem2 = rem % 320;
        int kc = rem2 / 64;
        int lane = rem2 % 64;
        int v = vt * 16 + (lane & 15);
        int kbase = kc * 32 + (lane >> 4) * 8;
        short8v out;
#pragma unroll
        for (int jj = 0; jj < 8; ++jj) {
            int kk = kbase + jj;
            float val = 0.f;
            if (v < NVERT) {
                if (kk < NPOSE)            val = P[(size_t)kk * (NVERT * 3) + v * 3 + k];
                else if (kk < NPOSE + 10)  val = S[v * 30 + k * 10 + (kk - NPOSE)];
                else if (kk == NPOSE + 10) val = V[v * 3 + k];
            }
            __hip_bfloat16 h = __float2bfloat16(val);
            out[jj] = *reinterpret_cast<short*>(&h);
        }
        ((short8v*)PtxF)[idx] = out;
    } else if (idx < NVT * 3 * 5 * 64 + NVT * 64) {
        int t = idx - NVT * 3 * 5 * 64;
        int vt = t / 64, lane = t % 64;
        int v = vt * 16 + (lane & 15);
        int jbase = (lane >> 4) * 8;
        short8v out;
#pragma unroll
        for (int jj = 0; jj < 8; ++jj) {
            int j = jbase + jj;
            float val = (j < 16 && v < NVERT) ? W[v * 16 + j] : 0.f;
            __hip_bfloat16 h = __float2bfloat16(val);
            out[jj] = *reinterpret_cast<short*>(&h);
        }
        ((short8v*)WF)[t] = out;
    }
}

__device__ __forceinline__ void rodrigues(float x, float y, float z, float R[9])
{
    float sq = x * x + y * y + z * z;
    float angle = sqrtf(sq + 1e-8f);
    float inv = 1.0f / angle;
    float ax = x * inv, ay = y * inv, az = z * inv;
    float c = cosf(angle), s = sinf(angle);
    float ic = 1.0f - c;
    R[0] = c + ic * ax * ax;      R[1] = ic * ax * ay - s * az; R[2] = ic * ax * az + s * ay;
    R[3] = ic * ax * ay + s * az; R[4] = c + ic * ay * ay;      R[5] = ic * ay * az - s * ax;
    R[6] = ic * ax * az - s * ay; R[7] = ic * ay * az + s * ax; R[8] = c + ic * az * az;
}

// write one joint's A_rel (3x4, bf16) directly in T-GEMM fragment order:
//   ATF[bt][mn][lane32][jj], lane32 = (i>>3)*16 + (b&15), jj = i&7
// (NO tvec fold — verbatim from passing r16)
__device__ __forceinline__ void writeATF(
    __hip_bfloat16* __restrict__ ATF, int b, int i,
    const float R[9], const float t[3], const float J[3])
{
    int bt = b >> 4;
    int lane32 = ((i >> 3) << 4) + (b & 15);
    size_t base = (((size_t)bt * 12) * 32 + lane32) * 8 + (i & 7);
    float vals[12];
#pragma unroll
    for (int m = 0; m < 3; ++m) {
        vals[m * 4 + 0] = R[m * 3 + 0];
        vals[m * 4 + 1] = R[m * 3 + 1];
        vals[m * 4 + 2] = R[m * 3 + 2];
        vals[m * 4 + 3] = t[m] - (R[m * 3 + 0] * J[0] + R[m * 3 + 1] * J[1] + R[m * 3 + 2] * J[2]);
    }
#pragma unroll
    for (int mn = 0; mn < 12; ++mn)
        ATF[base + (size_t)mn * 256] = __float2bfloat16(vals[mn]);
}

// ---------------------------------------------------------------------------
// Kernel B: Rodrigues + kinematic chain, one thread per (chain c, batch b).
// (verbatim from passing r16)
// ---------------------------------------------------------------------------
__global__ __launch_bounds__(256) void chain_kernel(
    const float* __restrict__ beta, const float* __restrict__ pose,
    const float* __restrict__ rvec, const float* __restrict__ tvec,
    const float* __restrict__ wsJS, __hip_bfloat16* __restrict__ pfx,
    __hip_bfloat16* __restrict__ ATF, float* __restrict__ out_joints)
{
    int t = blockIdx.x * 256 + threadIdx.x;   // [5][8192]
    int c = t >> 13;
    int b = t & (BATCH - 1);
    if (c >= 5) return;

    const int INVMAP[16] = {0, 5, 6, 7, 9, 10, 11, 17, 18, 19, 13, 14, 15, 1, 2, 3};

    float bt[10];
#pragma unroll
    for (int l = 0; l < 10; ++l) bt[l] = beta[b * 10 + l];

    float Jr0[3], Jrc[3][3];
#pragma unroll
    for (int k = 0; k < 3; ++k) {
        float s = wsJS[480 + k];
#pragma unroll
        for (int l = 0; l < 10; ++l) s += wsJS[k * 10 + l] * bt[l];
        Jr0[k] = s;
    }
#pragma unroll
    for (int sI = 0; sI < 3; ++sI) {
        int j = 3 * c + 1 + sI;
#pragma unroll
        for (int k = 0; k < 3; ++k) {
            float s = wsJS[480 + j * 3 + k];
#pragma unroll
            for (int l = 0; l < 10; ++l) s += wsJS[(j * 3 + k) * 10 + l] * bt[l];
            Jrc[sI][k] = s;
        }
    }

    float tv[3] = {tvec[b * 3 + 0], tvec[b * 3 + 1], tvec[b * 3 + 2]};

    float R0[9];
    rodrigues(rvec[b * 3 + 0], rvec[b * 3 + 1], rvec[b * 3 + 2], R0);
    float t0[3] = {Jr0[0], Jr0[1], Jr0[2]};

    __hip_bfloat16* pfb = pfx + (size_t)b * KEXT;
    float* jout = out_joints + (size_t)b * 63;

    if (c == 0) {
#pragma unroll
        for (int l = 0; l < 10; ++l) pfb[NPOSE + l] = __float2bfloat16(bt[l]);
        pfb[NPOSE + 10] = __float2bfloat16(1.0f);
#pragma unroll
        for (int l = NPOSE + 11; l < KEXT; ++l) pfb[l] = __float2bfloat16(0.0f);

#pragma unroll
        for (int k = 0; k < 3; ++k) jout[INVMAP[0] * 3 + k] = t0[k] + tv[k];
        writeATF(ATF, b, 0, R0, t0, Jr0);
    }

    float Rc[9], tc[3], prevJ[3];
#pragma unroll
    for (int q = 0; q < 9; ++q) Rc[q] = R0[q];
#pragma unroll
    for (int k = 0; k < 3; ++k) { tc[k] = t0[k]; prevJ[k] = Jr0[k]; }

#pragma unroll
    for (int s = 0; s < 3; ++s) {
        int i = 3 * c + 1 + s;
        float Ri[9];
        rodrigues(pose[b * 45 + (i - 1) * 3 + 0],
                  pose[b * 45 + (i - 1) * 3 + 1],
                  pose[b * 45 + (i - 1) * 3 + 2], Ri);
#pragma unroll
        for (int mn = 0; mn < 9; ++mn)
            pfb[(i - 1) * 9 + mn] =
                __float2bfloat16(Ri[mn] - ((mn == 0 || mn == 4 || mn == 8) ? 1.0f : 0.0f));

        float rel[3];
#pragma unroll
        for (int k = 0; k < 3; ++k) rel[k] = Jrc[s][k] - prevJ[k];

        float Rn[9], tn[3];
#pragma unroll
        for (int m = 0; m < 3; ++m) {
#pragma unroll
            for (int n = 0; n < 3; ++n)
                Rn[m * 3 + n] = Rc[m * 3 + 0] * Ri[0 + n] + Rc[m * 3 + 1] * Ri[3 + n] + Rc[m * 3 + 2] * Ri[6 + n];
            tn[m] = Rc[m * 3 + 0] * rel[0] + Rc[m * 3 + 1] * rel[1] + Rc[m * 3 + 2] * rel[2] + tc[m];
        }
#pragma unroll
        for (int q = 0; q < 9; ++q) Rc[q] = Rn[q];
#pragma unroll
        for (int k = 0; k < 3; ++k) { tc[k] = tn[k]; prevJ[k] = Jrc[s][k]; }

#pragma unroll
        for (int k = 0; k < 3; ++k) jout[INVMAP[i] * 3 + k] = tc[k] + tv[k];

        writeATF(ATF, b, i, Rc, tc, Jrc[s]);
    }
}

// ---------------------------------------------------------------------------
// per-WAVE full-tile stage: this wave issues all 16 chunks (1KB each) of
// v-tile vt into its own private LDS buffer. No inter-wave sharing.
// ---------------------------------------------------------------------------
__device__ __forceinline__ void stage_full(
    const __hip_bfloat16* __restrict__ PtxF,
    const __hip_bfloat16* __restrict__ WF,
    int vt, short* dst, int lane)
{
#pragma unroll
    for (int g = 0; g < 16; ++g) {
        const char* src = (g < 15)
            ? (const char*)PtxF + ((size_t)vt * 15 + g) * 1024
            : (const char*)WF + (size_t)vt * 1024;
        src += lane * 16;
        char* d = (char*)dst + g * 1024;   // wave-uniform base; HW adds lane*16
        __builtin_amdgcn_global_load_lds(
            (const __attribute__((address_space(1))) void*)src,
            (__attribute__((address_space(3))) void*)d,
            16, 0, 0);
    }
}

// ---------------------------------------------------------------------------
// Kernel C: all-MFMA verts kernel — BARRIER-FREE, per-wave-private staging.
// Each wave owns one bt and a private 2x16KB LDS double buffer (4 waves x
// 32KB = 128KB/block, 1 block/CU). Per iter: issue own stage(i+1) [16 loads,
// pinned oldest] -> ds_read own buf[i] + MFMA -> stores -> own vmcnt(4).
// NO s_barrier anywhere: waves de-phase so one wave's store/stage phase
// overlaps another's LDS/MFMA phase across the CU (attacks the phase-lock
// that six schedule experiments left intact).
// vmcnt accounting (per-wave): 16 loads precede >=4 unmergeable store
// instructions on every tile 0..48 (each has >=1 valid lane); outstanding<=4
// => the <=4 newest stores remain, all loads retired. Math/stores verbatim
// from passing r16.
// ---------------------------------------------------------------------------
__global__ __launch_bounds__(256, 1) void verts_kernel(
    const __hip_bfloat16* __restrict__ pfx,
    const __hip_bfloat16* __restrict__ PtxF,
    const __hip_bfloat16* __restrict__ WF,
    const __hip_bfloat16* __restrict__ ATF,
    const float* __restrict__ tvec,
    float* __restrict__ out_verts, float* __restrict__ out_joints)
{
    __shared__ __align__(16) short Bs[4][2][16 * 64 * 8];   // 4 waves x 2 x 16KB

    int tid = threadIdx.x;
    int lane = tid & 63;
    int wave = tid >> 6;
    int l15 = lane & 15;
    int lg  = lane >> 4;

    int bt = blockIdx.x * 4 + wave;   // wave-private batch tile, 0..511
    int b0 = bt * 16;
    int vg = blockIdx.y;              // 0..3

    int start = (vg == 0) ? 0 : 13 + (vg - 1) * 12;   // 0,13,25,37
    int count = (vg == 0) ? 13 : 12;                  // covers tiles 0..48

    // A-side operands (exact passing formulas), held for all v-tiles
    short8v hA[5];
#pragma unroll
    for (int kc = 0; kc < 5; ++kc)
        hA[kc] = *(const short8v*)(pfx + (size_t)(b0 + l15) * KEXT + kc * 32 + lg * 8);

    short8v tA[12];
#pragma unroll
    for (int mn = 0; mn < 12; ++mn)
        tA[mn] = *(const short8v*)(ATF + (((size_t)bt * 12 + mn) * 32 + (lane & 31)) * 8);

    float tv[4][3];
#pragma unroll
    for (int r = 0; r < 4; ++r) {
        int b = b0 + lg * 4 + r;
#pragma unroll
        for (int m = 0; m < 3; ++m) tv[r][m] = tvec[b * 3 + m];
    }

    // prologue: stage own tile 0, wait own loads (per-wave, no barrier)
    stage_full(PtxF, WF, start, &Bs[wave][0][0], lane);
    asm volatile("s_waitcnt vmcnt(0)" ::: "memory");
    __builtin_amdgcn_sched_barrier(0);

    for (int i = 0; i < count; ++i) {
        int vt = start + i;
        const short* cur = &Bs[wave][i & 1][0];

        // issue own next tile's stage FIRST (16 loads, pinned oldest)
        if (i + 1 < count)
            stage_full(PtxF, WF, vt + 1, &Bs[wave][(i + 1) & 1][0], lane);
        __builtin_amdgcn_sched_barrier(0);

        // batched ds_read: all 16 fragments issued back-to-back
        short8v hB[15];
#pragma unroll
        for (int f = 0; f < 15; ++f)
            hB[f] = *(const short8v*)(cur + f * 512 + lane * 8);
        short8v wf = *(const short8v*)(cur + 15 * 512 + lane * 8);

        float4v hacc[3], Tacc[12];
#pragma unroll
        for (int k = 0; k < 3; ++k) hacc[k] = (float4v){0.f, 0.f, 0.f, 0.f};
#pragma unroll
        for (int mn = 0; mn < 12; ++mn) Tacc[mn] = (float4v){0.f, 0.f, 0.f, 0.f};

#pragma unroll
        for (int k = 0; k < 3; ++k)
#pragma unroll
            for (int kc = 0; kc < 5; ++kc)
                hacc[k] = __builtin_amdgcn_mfma_f32_16x16x32_bf16(
                    hA[kc], hB[k * 5 + kc], hacc[k], 0, 0, 0);

#pragma unroll
        for (int mn = 0; mn < 12; ++mn)
            Tacc[mn] = __builtin_amdgcn_mfma_f32_16x16x32_bf16(
                tA[mn], wf, Tacc[mn], 0, 0, 0);

        int v = vt * 16 + l15;
        int dest = (v == 745) ? 4 : (v == 333) ? 8 : (v == 444) ? 12 :
                   (v == 555) ? 16 : (v == 672) ? 20 : -1;

        if (v < NVERT) {
#pragma unroll
            for (int r = 0; r < 4; ++r) {
                float h0 = hacc[0][r], h1 = hacc[1][r], h2 = hacc[2][r];
                float e0 = Tacc[0][r] * h0 + Tacc[1][r] * h1 + Tacc[2][r]  * h2 + Tacc[3][r]  + tv[r][0];
                float e1 = Tacc[4][r] * h0 + Tacc[5][r] * h1 + Tacc[6][r]  * h2 + Tacc[7][r]  + tv[r][1];
                float e2 = Tacc[8][r] * h0 + Tacc[9][r] * h1 + Tacc[10][r] * h2 + Tacc[11][r] + tv[r][2];
                int b = b0 + lg * 4 + r;
                size_t idx = ((size_t)b * NVERT + v) * 3;
                out_verts[idx + 0] = e0;
                out_verts[idx + 1] = e1;
                out_verts[idx + 2] = e2;
                if (dest >= 0) {
                    size_t jidx = (size_t)b * 63 + dest * 3;
                    out_joints[jidx + 0] = e0;
                    out_joints[jidx + 1] = e1;
                    out_joints[jidx + 2] = e2;
                }
            }
        }

        // per-wave counted wait: own 16 loads are oldest, >=4 own store
        // instructions newest; outstanding<=4 => next tile landed. No barrier.
        if (i + 1 < count) {
            asm volatile("s_waitcnt vmcnt(4)" ::: "memory");
            __builtin_amdgcn_sched_barrier(0);
        }
    }
}

extern "C" void kernel_launch(void* const* d_in, const int* in_sizes, int n_in,
                              void* d_out, int out_size, void* d_ws, size_t ws_size,
                              hipStream_t stream)
{
    const float* beta  = (const float*)d_in[0];
    const float* pose  = (const float*)d_in[1];
    const float* rvec  = (const float*)d_in[2];
    const float* tvec  = (const float*)d_in[3];
    const float* V     = (const float*)d_in[4];
    const float* S     = (const float*)d_in[5];
    const float* P     = (const float*)d_in[6];
    const float* J_reg = (const float*)d_in[7];
    const float* W     = (const float*)d_in[8];

    float* out    = (float*)d_out;
    float* verts  = out;
    float* joints = out + (size_t)BATCH * NVERT * 3;

    char* wsb = (char*)d_ws;
    float*          wsJS = (float*)(wsb + WSB_JS);
    __hip_bfloat16* pfx  = (__hip_bfloat16*)(wsb + WSB_PFX);
    __hip_bfloat16* PtxF = (__hip_bfloat16*)(wsb + WSB_PTXF);
    __hip_bfloat16* WFp  = (__hip_bfloat16*)(wsb + WSB_WF);
    __hip_bfloat16* ATF  = (__hip_bfloat16*)(wsb + WSB_ATF);

    hipLaunchKernelGGL(prep_kernel, dim3(340), dim3(256), 0, stream,
                       S, V, J_reg, P, W, wsJS, PtxF, WFp);
    hipLaunchKernelGGL(chain_kernel, dim3(160), dim3(256), 0, stream,
                       beta, pose, rvec, tvec, wsJS, pfx, ATF, joints);
    hipLaunchKernelGGL(verts_kernel, dim3(128, 4), dim3(256), 0, stream,
                       pfx, PtxF, WFp, ATF, tvec, verts, joints);
}

// Round 20
// 44.129 us; speedup vs baseline: 1.3133x; 1.3133x over previous
//
#include <hip/hip_runtime.h>
#include <hip/hip_bf16.h>

typedef __attribute__((ext_vector_type(8))) short short8v;
typedef __attribute__((ext_vector_type(4))) float float4v;

#define BATCH 8192
#define NVERT 778
#define NJOINT 16
#define NPOSE 135
#define KEXT  160          // 135 pose + 10 beta + 1 const + 14 zero
#define NVT   52           // vertex 16-tiles (52*16 = 832; 49 valid)

// workspace byte offsets (all 16B aligned)
#define WSB_JS    0u
#define WSB_PFX   4096u                        // bf16 [8192][160]
#define WSB_A     (WSB_PFX  + 2621440u)        // (unused, kept for layout)
#define WSB_PTXF  (WSB_A    + 6291456u)        // bf16 [52][3][5][64][8]  h-B frags
#define WSB_WF    (WSB_PTXF + 798720u)         // bf16 [52][64][8]        T-B frags (W)
#define WSB_ATF   (WSB_WF   + 53248u)          // bf16 [512][12][32][8]   T-A frags

// ---------------------------------------------------------------------------
// Kernel A (merged): blocks [0,132) fold J_reg into S,V; blocks [132,340)
// build fragment-order PtxF / WF.   (verbatim from passing r16)
// ---------------------------------------------------------------------------
__global__ __launch_bounds__(256) void prep_kernel(
    const float* __restrict__ S, const float* __restrict__ V,
    const float* __restrict__ J_reg, const float* __restrict__ P,
    const float* __restrict__ W,
    float* __restrict__ wsJS, __hip_bfloat16* __restrict__ PtxF,
    __hip_bfloat16* __restrict__ WF)
{
    if (blockIdx.x < 132) {
        int o = blockIdx.x * 4 + (threadIdx.x >> 6);
        int lane = threadIdx.x & 63;
        float s = 0.f;
        if (o < 480) {
            int j = o / 30, k = (o / 10) % 3, l = o % 10;
            for (int v = lane; v < NVERT; v += 64)
                s += J_reg[j * NVERT + v] * S[v * 30 + k * 10 + l];
        } else if (o < 528) {
            int o2 = o - 480;
            int j = o2 / 3, k = o2 % 3;
            for (int v = lane; v < NVERT; v += 64)
                s += J_reg[j * NVERT + v] * V[v * 3 + k];
        }
#pragma unroll
        for (int m = 32; m >= 1; m >>= 1) s += __shfl_xor(s, m, 64);
        if (lane == 0 && o < 528) wsJS[o] = s;
        return;
    }

    int idx = (blockIdx.x - 132) * 256 + threadIdx.x;
    if (idx < NVT * 3 * 5 * 64) {
        int vt = idx / 960;
        int rem = idx % 960;
        int k = rem / 320;
        int rem2 = rem % 320;
        int kc = rem2 / 64;
        int lane = rem2 % 64;
        int v = vt * 16 + (lane & 15);
        int kbase = kc * 32 + (lane >> 4) * 8;
        short8v out;
#pragma unroll
        for (int jj = 0; jj < 8; ++jj) {
            int kk = kbase + jj;
            float val = 0.f;
            if (v < NVERT) {
                if (kk < NPOSE)            val = P[(size_t)kk * (NVERT * 3) + v * 3 + k];
                else if (kk < NPOSE + 10)  val = S[v * 30 + k * 10 + (kk - NPOSE)];
                else if (kk == NPOSE + 10) val = V[v * 3 + k];
            }
            __hip_bfloat16 h = __float2bfloat16(val);
            out[jj] = *reinterpret_cast<short*>(&h);
        }
        ((short8v*)PtxF)[idx] = out;
    } else if (idx < NVT * 3 * 5 * 64 + NVT * 64) {
        int t = idx - NVT * 3 * 5 * 64;
        int vt = t / 64, lane = t % 64;
        int v = vt * 16 + (lane & 15);
        int jbase = (lane >> 4) * 8;
        short8v out;
#pragma unroll
        for (int jj = 0; jj < 8; ++jj) {
            int j = jbase + jj;
            float val = (j < 16 && v < NVERT) ? W[v * 16 + j] : 0.f;
            __hip_bfloat16 h = __float2bfloat16(val);
            out[jj] = *reinterpret_cast<short*>(&h);
        }
        ((short8v*)WF)[t] = out;
    }
}

__device__ __forceinline__ void rodrigues(float x, float y, float z, float R[9])
{
    float sq = x * x + y * y + z * z;
    float angle = sqrtf(sq + 1e-8f);
    float inv = 1.0f / angle;
    float ax = x * inv, ay = y * inv, az = z * inv;
    float c = cosf(angle), s = sinf(angle);
    float ic = 1.0f - c;
    R[0] = c + ic * ax * ax;      R[1] = ic * ax * ay - s * az; R[2] = ic * ax * az + s * ay;
    R[3] = ic * ax * ay + s * az; R[4] = c + ic * ay * ay;      R[5] = ic * ay * az - s * ax;
    R[6] = ic * ax * az - s * ay; R[7] = ic * ay * az + s * ax; R[8] = c + ic * az * az;
}

// write one joint's A_rel (3x4, bf16) in T-GEMM fragment order, with tvec
// FOLDED into the translation column (sum_j W[v,j]==1; this exact fold
// passed correctness in rounds 7 and 15 at absmax 0.03125):
//   ATF[bt][mn][lane32][jj], lane32 = (i>>3)*16 + (b&15), jj = i&7
__device__ __forceinline__ void writeATF(
    __hip_bfloat16* __restrict__ ATF, int b, int i,
    const float R[9], const float t[3], const float J[3], const float tv[3])
{
    int bt = b >> 4;
    int lane32 = ((i >> 3) << 4) + (b & 15);
    size_t base = (((size_t)bt * 12) * 32 + lane32) * 8 + (i & 7);
    float vals[12];
#pragma unroll
    for (int m = 0; m < 3; ++m) {
        vals[m * 4 + 0] = R[m * 3 + 0];
        vals[m * 4 + 1] = R[m * 3 + 1];
        vals[m * 4 + 2] = R[m * 3 + 2];
        vals[m * 4 + 3] = t[m] + tv[m] - (R[m * 3 + 0] * J[0] + R[m * 3 + 1] * J[1] + R[m * 3 + 2] * J[2]);
    }
#pragma unroll
    for (int mn = 0; mn < 12; ++mn)
        ATF[base + (size_t)mn * 256] = __float2bfloat16(vals[mn]);
}

// ---------------------------------------------------------------------------
// Kernel B: Rodrigues + kinematic chain, one thread per (chain c, batch b).
// (verbatim math; ATF carries the r7/r15-proven tvec fold)
// ---------------------------------------------------------------------------
__global__ __launch_bounds__(256) void chain_kernel(
    const float* __restrict__ beta, const float* __restrict__ pose,
    const float* __restrict__ rvec, const float* __restrict__ tvec,
    const float* __restrict__ wsJS, __hip_bfloat16* __restrict__ pfx,
    __hip_bfloat16* __restrict__ ATF, float* __restrict__ out_joints)
{
    int t = blockIdx.x * 256 + threadIdx.x;   // [5][8192]
    int c = t >> 13;
    int b = t & (BATCH - 1);
    if (c >= 5) return;

    const int INVMAP[16] = {0, 5, 6, 7, 9, 10, 11, 17, 18, 19, 13, 14, 15, 1, 2, 3};

    float bt[10];
#pragma unroll
    for (int l = 0; l < 10; ++l) bt[l] = beta[b * 10 + l];

    float Jr0[3], Jrc[3][3];
#pragma unroll
    for (int k = 0; k < 3; ++k) {
        float s = wsJS[480 + k];
#pragma unroll
        for (int l = 0; l < 10; ++l) s += wsJS[k * 10 + l] * bt[l];
        Jr0[k] = s;
    }
#pragma unroll
    for (int sI = 0; sI < 3; ++sI) {
        int j = 3 * c + 1 + sI;
#pragma unroll
        for (int k = 0; k < 3; ++k) {
            float s = wsJS[480 + j * 3 + k];
#pragma unroll
            for (int l = 0; l < 10; ++l) s += wsJS[(j * 3 + k) * 10 + l] * bt[l];
            Jrc[sI][k] = s;
        }
    }

    float tv[3] = {tvec[b * 3 + 0], tvec[b * 3 + 1], tvec[b * 3 + 2]};

    float R0[9];
    rodrigues(rvec[b * 3 + 0], rvec[b * 3 + 1], rvec[b * 3 + 2], R0);
    float t0[3] = {Jr0[0], Jr0[1], Jr0[2]};

    __hip_bfloat16* pfb = pfx + (size_t)b * KEXT;
    float* jout = out_joints + (size_t)b * 63;

    if (c == 0) {
#pragma unroll
        for (int l = 0; l < 10; ++l) pfb[NPOSE + l] = __float2bfloat16(bt[l]);
        pfb[NPOSE + 10] = __float2bfloat16(1.0f);
#pragma unroll
        for (int l = NPOSE + 11; l < KEXT; ++l) pfb[l] = __float2bfloat16(0.0f);

#pragma unroll
        for (int k = 0; k < 3; ++k) jout[INVMAP[0] * 3 + k] = t0[k] + tv[k];
        writeATF(ATF, b, 0, R0, t0, Jr0, tv);
    }

    float Rc[9], tc[3], prevJ[3];
#pragma unroll
    for (int q = 0; q < 9; ++q) Rc[q] = R0[q];
#pragma unroll
    for (int k = 0; k < 3; ++k) { tc[k] = t0[k]; prevJ[k] = Jr0[k]; }

#pragma unroll
    for (int s = 0; s < 3; ++s) {
        int i = 3 * c + 1 + s;
        float Ri[9];
        rodrigues(pose[b * 45 + (i - 1) * 3 + 0],
                  pose[b * 45 + (i - 1) * 3 + 1],
                  pose[b * 45 + (i - 1) * 3 + 2], Ri);
#pragma unroll
        for (int mn = 0; mn < 9; ++mn)
            pfb[(i - 1) * 9 + mn] =
                __float2bfloat16(Ri[mn] - ((mn == 0 || mn == 4 || mn == 8) ? 1.0f : 0.0f));

        float rel[3];
#pragma unroll
        for (int k = 0; k < 3; ++k) rel[k] = Jrc[s][k] - prevJ[k];

        float Rn[9], tn[3];
#pragma unroll
        for (int m = 0; m < 3; ++m) {
#pragma unroll
            for (int n = 0; n < 3; ++n)
                Rn[m * 3 + n] = Rc[m * 3 + 0] * Ri[0 + n] + Rc[m * 3 + 1] * Ri[3 + n] + Rc[m * 3 + 2] * Ri[6 + n];
            tn[m] = Rc[m * 3 + 0] * rel[0] + Rc[m * 3 + 1] * rel[1] + Rc[m * 3 + 2] * rel[2] + tc[m];
        }
#pragma unroll
        for (int q = 0; q < 9; ++q) Rc[q] = Rn[q];
#pragma unroll
        for (int k = 0; k < 3; ++k) { tc[k] = tn[k]; prevJ[k] = Jrc[s][k]; }

#pragma unroll
        for (int k = 0; k < 3; ++k) jout[INVMAP[i] * 3 + k] = tc[k] + tv[k];

        writeATF(ATF, b, i, Rc, tc, Jrc[s], tv);
    }
}

// ---------------------------------------------------------------------------
// issue the 16KB fragment set of v-tile vt into LDS buffer dst (async,
// global_load_lds width 16): wave w stages chunks [4w, 4w+4), 1KB each.
// ---------------------------------------------------------------------------
__device__ __forceinline__ void stage_tile(
    const __hip_bfloat16* __restrict__ PtxF,
    const __hip_bfloat16* __restrict__ WF,
    int vt, short* dst, int wave, int lane)
{
#pragma unroll
    for (int c = 0; c < 4; ++c) {
        int g = wave * 4 + c;   // 0..15 (wave-uniform)
        const char* src = (g < 15)
            ? (const char*)PtxF + ((size_t)vt * 15 + g) * 1024
            : (const char*)WF + (size_t)vt * 1024;
        src += lane * 16;
        char* d = (char*)dst + g * 1024;   // wave-uniform base; HW adds lane*16
        __builtin_amdgcn_global_load_lds(
            (const __attribute__((address_space(1))) void*)src,
            (__attribute__((address_space(3))) void*)d,
            16, 0, 0);
    }
}

// ---------------------------------------------------------------------------
// Kernel C: all-MFMA verts kernel — r16 structure (depth-3 pipeline, counted
// vmcnt(8), raw barriers) with ONE mechanism changed: register diet ->
// 3 blocks/CU (store-pipe concurrency).
//   * hB consumed load-adjacent (r15/r18-passing pattern; frees ~56 VGPR;
//     tA stays RESIDENT — r18's streaming mistake avoided).
//   * tvec folded into ATF (r7/r15-passing; frees tv[4][3] + epilogue adds).
//   * __launch_bounds__(256,3); est ~155 VGPR (under the 168 cap, unlike r15).
//   * grid (128,6) = 768 blocks so a 3rd block/CU is available; LDS 48KB x 3
//     = 144KB <= 160KB.
// vmcnt(8) accounting unchanged from r16: stage(i+2)'s 4 loads pinned oldest,
// >=4 unmergeable stores follow; outstanding<=8 retires L_{i+1} and older.
// ---------------------------------------------------------------------------
__global__ __launch_bounds__(256, 3) void verts_kernel(
    const __hip_bfloat16* __restrict__ pfx,
    const __hip_bfloat16* __restrict__ PtxF,
    const __hip_bfloat16* __restrict__ WF,
    const __hip_bfloat16* __restrict__ ATF,
    float* __restrict__ out_verts, float* __restrict__ out_joints)
{
    __shared__ __align__(16) short Bs[3][16 * 64 * 8];   // 3 x 16 KB

    int tid = threadIdx.x;
    int lane = tid & 63;
    int wave = tid >> 6;
    int l15 = lane & 15;
    int lg  = lane >> 4;

    int bt = blockIdx.x * 4 + wave;   // wave-private batch tile, 0..511
    int b0 = bt * 16;
    int vg = blockIdx.y;              // 0..5

    int start = (vg == 0) ? 0 : 9 + (vg - 1) * 8;   // 0,9,17,25,33,41
    int count = (vg == 0) ? 9 : 8;                  // covers tiles 0..48

    // A-side operands (exact passing formulas), held for all v-tiles
    short8v hA[5];
#pragma unroll
    for (int kc = 0; kc < 5; ++kc)
        hA[kc] = *(const short8v*)(pfx + (size_t)(b0 + l15) * KEXT + kc * 32 + lg * 8);

    short8v tA[12];
#pragma unroll
    for (int mn = 0; mn < 12; ++mn)
        tA[mn] = *(const short8v*)(ATF + (((size_t)bt * 12 + mn) * 32 + (lane & 31)) * 8);

    // prologue: stage tiles 0 and 1; wait only for tile 0 (L_1 stays in flight)
    stage_tile(PtxF, WF, start, &Bs[0][0], wave, lane);
    if (count > 1)
        stage_tile(PtxF, WF, start + 1, &Bs[1][0], wave, lane);
    asm volatile("s_waitcnt vmcnt(4)" ::: "memory");
    __builtin_amdgcn_s_barrier();
    __builtin_amdgcn_sched_barrier(0);

    for (int i = 0; i < count; ++i) {
        int vt = start + i;
        const short* cur = &Bs[i % 3][0];

        // issue stage(i+2) FIRST (4 loads/wave, async), pinned oldest
        if (i + 2 < count)
            stage_tile(PtxF, WF, vt + 2, &Bs[(i + 2) % 3][0], wave, lane);
        __builtin_amdgcn_sched_barrier(0);

        // wf first (feeds 12 independent MFMAs), then T-GEMM
        short8v wf = *(const short8v*)(cur + 15 * 512 + lane * 8);

        float4v Tacc[12];
#pragma unroll
        for (int mn = 0; mn < 12; ++mn) Tacc[mn] = (float4v){0.f, 0.f, 0.f, 0.f};
#pragma unroll
        for (int mn = 0; mn < 12; ++mn)
            Tacc[mn] = __builtin_amdgcn_mfma_f32_16x16x32_bf16(
                tA[mn], wf, Tacc[mn], 0, 0, 0);

        // h-GEMM: load-adjacent hB (single-use register, dies immediately)
        float4v hacc[3];
#pragma unroll
        for (int k = 0; k < 3; ++k) hacc[k] = (float4v){0.f, 0.f, 0.f, 0.f};
#pragma unroll
        for (int f = 0; f < 15; ++f) {
            short8v hB = *(const short8v*)(cur + f * 512 + lane * 8);
            hacc[f / 5] = __builtin_amdgcn_mfma_f32_16x16x32_bf16(
                hA[f % 5], hB, hacc[f / 5], 0, 0, 0);
        }

        int v = vt * 16 + l15;
        int dest = (v == 745) ? 4 : (v == 333) ? 8 : (v == 444) ? 12 :
                   (v == 555) ? 16 : (v == 672) ? 20 : -1;

        if (v < NVERT) {
#pragma unroll
            for (int r = 0; r < 4; ++r) {
                float h0 = hacc[0][r], h1 = hacc[1][r], h2 = hacc[2][r];
                float e0 = Tacc[0][r] * h0 + Tacc[1][r] * h1 + Tacc[2][r]  * h2 + Tacc[3][r];
                float e1 = Tacc[4][r] * h0 + Tacc[5][r] * h1 + Tacc[6][r]  * h2 + Tacc[7][r];
                float e2 = Tacc[8][r] * h0 + Tacc[9][r] * h1 + Tacc[10][r] * h2 + Tacc[11][r];
                int b = b0 + lg * 4 + r;
                size_t idx = ((size_t)b * NVERT + v) * 3;
                out_verts[idx + 0] = e0;
                out_verts[idx + 1] = e1;
                out_verts[idx + 2] = e2;
                if (dest >= 0) {
                    size_t jidx = (size_t)b * 63 + dest * 3;
                    out_joints[jidx + 0] = e0;
                    out_joints[jidx + 1] = e1;
                    out_joints[jidx + 2] = e2;
                }
            }
        }

        // counted wait at depth 3 (r16-proven): newest 8 outstanding =
        // S_i(>=4) + L_{i+2}(4); L_{i+1} and older provably retired.
        if (i + 1 < count) {
            asm volatile("s_waitcnt vmcnt(8)" ::: "memory");
            __builtin_amdgcn_s_barrier();
            __builtin_amdgcn_sched_barrier(0);
        }
    }
}

extern "C" void kernel_launch(void* const* d_in, const int* in_sizes, int n_in,
                              void* d_out, int out_size, void* d_ws, size_t ws_size,
                              hipStream_t stream)
{
    const float* beta  = (const float*)d_in[0];
    const float* pose  = (const float*)d_in[1];
    const float* rvec  = (const float*)d_in[2];
    const float* tvec  = (const float*)d_in[3];
    const float* V     = (const float*)d_in[4];
    const float* S     = (const float*)d_in[5];
    const float* P     = (const float*)d_in[6];
    const float* J_reg = (const float*)d_in[7];
    const float* W     = (const float*)d_in[8];

    float* out    = (float*)d_out;
    float* verts  = out;
    float* joints = out + (size_t)BATCH * NVERT * 3;

    char* wsb = (char*)d_ws;
    float*          wsJS = (float*)(wsb + WSB_JS);
    __hip_bfloat16* pfx  = (__hip_bfloat16*)(wsb + WSB_PFX);
    __hip_bfloat16* PtxF = (__hip_bfloat16*)(wsb + WSB_PTXF);
    __hip_bfloat16* WFp  = (__hip_bfloat16*)(wsb + WSB_WF);
    __hip_bfloat16* ATF  = (__hip_bfloat16*)(wsb + WSB_ATF);

    hipLaunchKernelGGL(prep_kernel, dim3(340), dim3(256), 0, stream,
                       S, V, J_reg, P, W, wsJS, PtxF, WFp);
    hipLaunchKernelGGL(chain_kernel, dim3(160), dim3(256), 0, stream,
                       beta, pose, rvec, tvec, wsJS, pfx, ATF, joints);
    hipLaunchKernelGGL(verts_kernel, dim3(128, 6), dim3(256), 0, stream,
                       pfx, PtxF, WFp, ATF, verts, joints);
}

// Round 21
// 42.344 us; speedup vs baseline: 1.3687x; 1.0422x over previous
//
#include <hip/hip_runtime.h>
#include <hip/hip_bf16.h>

typedef __attribute__((ext_vector_type(8))) short short8v;
typedef __attribute__((ext_vector_type(4))) float float4v;

#define BATCH 8192
#define NVERT 778
#define NJOINT 16
#define NPOSE 135
#define KEXT  160          // 135 pose + 10 beta + 1 const + 14 zero
#define NVT   52           // vertex 16-tiles (52*16 = 832; 49 valid)

// workspace byte offsets (all 16B aligned)
#define WSB_JS    0u
#define WSB_PFX   4096u                        // bf16 [8192][160]
#define WSB_A     (WSB_PFX  + 2621440u)        // (unused, kept for layout)
#define WSB_PTXF  (WSB_A    + 6291456u)        // bf16 [52][3][5][64][8]  h-B frags
#define WSB_WF    (WSB_PTXF + 798720u)         // bf16 [52][64][8]        T-B frags (W)
#define WSB_ATF   (WSB_WF   + 53248u)          // bf16 [512][12][32][8]   T-A frags

// ---------------------------------------------------------------------------
// Kernel A (merged): blocks [0,132) fold J_reg into S,V; blocks [132,340)
// build fragment-order PtxF / WF.
// ---------------------------------------------------------------------------
__global__ __launch_bounds__(256) void prep_kernel(
    const float* __restrict__ S, const float* __restrict__ V,
    const float* __restrict__ J_reg, const float* __restrict__ P,
    const float* __restrict__ W,
    float* __restrict__ wsJS, __hip_bfloat16* __restrict__ PtxF,
    __hip_bfloat16* __restrict__ WF)
{
    if (blockIdx.x < 132) {
        int o = blockIdx.x * 4 + (threadIdx.x >> 6);
        int lane = threadIdx.x & 63;
        float s = 0.f;
        if (o < 480) {
            int j = o / 30, k = (o / 10) % 3, l = o % 10;
            for (int v = lane; v < NVERT; v += 64)
                s += J_reg[j * NVERT + v] * S[v * 30 + k * 10 + l];
        } else if (o < 528) {
            int o2 = o - 480;
            int j = o2 / 3, k = o2 % 3;
            for (int v = lane; v < NVERT; v += 64)
                s += J_reg[j * NVERT + v] * V[v * 3 + k];
        }
#pragma unroll
        for (int m = 32; m >= 1; m >>= 1) s += __shfl_xor(s, m, 64);
        if (lane == 0 && o < 528) wsJS[o] = s;
        return;
    }

    int idx = (blockIdx.x - 132) * 256 + threadIdx.x;
    if (idx < NVT * 3 * 5 * 64) {
        int vt = idx / 960;
        int rem = idx % 960;
        int k = rem / 320;
        int rem2 = rem % 320;
        int kc = rem2 / 64;
        int lane = rem2 % 64;
        int v = vt * 16 + (lane & 15);
        int kbase = kc * 32 + (lane >> 4) * 8;
        short8v out;
#pragma unroll
        for (int jj = 0; jj < 8; ++jj) {
            int kk = kbase + jj;
            float val = 0.f;
            if (v < NVERT) {
                if (kk < NPOSE)            val = P[(size_t)kk * (NVERT * 3) + v * 3 + k];
                else if (kk < NPOSE + 10)  val = S[v * 30 + k * 10 + (kk - NPOSE)];
                else if (kk == NPOSE + 10) val = V[v * 3 + k];
            }
            __hip_bfloat16 h = __float2bfloat16(val);
            out[jj] = *reinterpret_cast<short*>(&h);
        }
        ((short8v*)PtxF)[idx] = out;
    } else if (idx < NVT * 3 * 5 * 64 + NVT * 64) {
        int t = idx - NVT * 3 * 5 * 64;
        int vt = t / 64, lane = t % 64;
        int v = vt * 16 + (lane & 15);
        int jbase = (lane >> 4) * 8;
        short8v out;
#pragma unroll
        for (int jj = 0; jj < 8; ++jj) {
            int j = jbase + jj;
            float val = (j < 16 && v < NVERT) ? W[v * 16 + j] : 0.f;
            __hip_bfloat16 h = __float2bfloat16(val);
            out[jj] = *reinterpret_cast<short*>(&h);
        }
        ((short8v*)WF)[t] = out;
    }
}

__device__ __forceinline__ void rodrigues(float x, float y, float z, float R[9])
{
    float sq = x * x + y * y + z * z;
    float angle = sqrtf(sq + 1e-8f);
    float inv = 1.0f / angle;
    float ax = x * inv, ay = y * inv, az = z * inv;
    float c = cosf(angle), s = sinf(angle);
    float ic = 1.0f - c;
    R[0] = c + ic * ax * ax;      R[1] = ic * ax * ay - s * az; R[2] = ic * ax * az + s * ay;
    R[3] = ic * ax * ay + s * az; R[4] = c + ic * ay * ay;      R[5] = ic * ay * az - s * ax;
    R[6] = ic * ax * az - s * ay; R[7] = ic * ay * az + s * ax; R[8] = c + ic * az * az;
}

// write one joint's A_rel (3x4, bf16) directly in T-GEMM fragment order:
//   ATF[bt][mn][lane32][jj], lane32 = (i>>3)*16 + (b&15), jj = i&7
__device__ __forceinline__ void writeATF(
    __hip_bfloat16* __restrict__ ATF, int b, int i,
    const float R[9], const float t[3], const float J[3])
{
    int bt = b >> 4;
    int lane32 = ((i >> 3) << 4) + (b & 15);
    size_t base = (((size_t)bt * 12) * 32 + lane32) * 8 + (i & 7);
    float vals[12];
#pragma unroll
    for (int m = 0; m < 3; ++m) {
        vals[m * 4 + 0] = R[m * 3 + 0];
        vals[m * 4 + 1] = R[m * 3 + 1];
        vals[m * 4 + 2] = R[m * 3 + 2];
        vals[m * 4 + 3] = t[m] - (R[m * 3 + 0] * J[0] + R[m * 3 + 1] * J[1] + R[m * 3 + 2] * J[2]);
    }
#pragma unroll
    for (int mn = 0; mn < 12; ++mn)
        ATF[base + (size_t)mn * 256] = __float2bfloat16(vals[mn]);
}

// ---------------------------------------------------------------------------
// Kernel B: Rodrigues + kinematic chain, one thread per (chain c, batch b).
// ---------------------------------------------------------------------------
__global__ __launch_bounds__(256) void chain_kernel(
    const float* __restrict__ beta, const float* __restrict__ pose,
    const float* __restrict__ rvec, const float* __restrict__ tvec,
    const float* __restrict__ wsJS, __hip_bfloat16* __restrict__ pfx,
    __hip_bfloat16* __restrict__ ATF, float* __restrict__ out_joints)
{
    int t = blockIdx.x * 256 + threadIdx.x;   // [5][8192]
    int c = t >> 13;
    int b = t & (BATCH - 1);
    if (c >= 5) return;

    const int INVMAP[16] = {0, 5, 6, 7, 9, 10, 11, 17, 18, 19, 13, 14, 15, 1, 2, 3};

    float bt[10];
#pragma unroll
    for (int l = 0; l < 10; ++l) bt[l] = beta[b * 10 + l];

    float Jr0[3], Jrc[3][3];
#pragma unroll
    for (int k = 0; k < 3; ++k) {
        float s = wsJS[480 + k];
#pragma unroll
        for (int l = 0; l < 10; ++l) s += wsJS[k * 10 + l] * bt[l];
        Jr0[k] = s;
    }
#pragma unroll
    for (int sI = 0; sI < 3; ++sI) {
        int j = 3 * c + 1 + sI;
#pragma unroll
        for (int k = 0; k < 3; ++k) {
            float s = wsJS[480 + j * 3 + k];
#pragma unroll
            for (int l = 0; l < 10; ++l) s += wsJS[(j * 3 + k) * 10 + l] * bt[l];
            Jrc[sI][k] = s;
        }
    }

    float tv[3] = {tvec[b * 3 + 0], tvec[b * 3 + 1], tvec[b * 3 + 2]};

    float R0[9];
    rodrigues(rvec[b * 3 + 0], rvec[b * 3 + 1], rvec[b * 3 + 2], R0);
    float t0[3] = {Jr0[0], Jr0[1], Jr0[2]};

    __hip_bfloat16* pfb = pfx + (size_t)b * KEXT;
    float* jout = out_joints + (size_t)b * 63;

    if (c == 0) {
#pragma unroll
        for (int l = 0; l < 10; ++l) pfb[NPOSE + l] = __float2bfloat16(bt[l]);
        pfb[NPOSE + 10] = __float2bfloat16(1.0f);
#pragma unroll
        for (int l = NPOSE + 11; l < KEXT; ++l) pfb[l] = __float2bfloat16(0.0f);

#pragma unroll
        for (int k = 0; k < 3; ++k) jout[INVMAP[0] * 3 + k] = t0[k] + tv[k];
        writeATF(ATF, b, 0, R0, t0, Jr0);
    }

    float Rc[9], tc[3], prevJ[3];
#pragma unroll
    for (int q = 0; q < 9; ++q) Rc[q] = R0[q];
#pragma unroll
    for (int k = 0; k < 3; ++k) { tc[k] = t0[k]; prevJ[k] = Jr0[k]; }

#pragma unroll
    for (int s = 0; s < 3; ++s) {
        int i = 3 * c + 1 + s;
        float Ri[9];
        rodrigues(pose[b * 45 + (i - 1) * 3 + 0],
                  pose[b * 45 + (i - 1) * 3 + 1],
                  pose[b * 45 + (i - 1) * 3 + 2], Ri);
#pragma unroll
        for (int mn = 0; mn < 9; ++mn)
            pfb[(i - 1) * 9 + mn] =
                __float2bfloat16(Ri[mn] - ((mn == 0 || mn == 4 || mn == 8) ? 1.0f : 0.0f));

        float rel[3];
#pragma unroll
        for (int k = 0; k < 3; ++k) rel[k] = Jrc[s][k] - prevJ[k];

        float Rn[9], tn[3];
#pragma unroll
        for (int m = 0; m < 3; ++m) {
#pragma unroll
            for (int n = 0; n < 3; ++n)
                Rn[m * 3 + n] = Rc[m * 3 + 0] * Ri[0 + n] + Rc[m * 3 + 1] * Ri[3 + n] + Rc[m * 3 + 2] * Ri[6 + n];
            tn[m] = Rc[m * 3 + 0] * rel[0] + Rc[m * 3 + 1] * rel[1] + Rc[m * 3 + 2] * rel[2] + tc[m];
        }
#pragma unroll
        for (int q = 0; q < 9; ++q) Rc[q] = Rn[q];
#pragma unroll
        for (int k = 0; k < 3; ++k) { tc[k] = tn[k]; prevJ[k] = Jrc[s][k]; }

#pragma unroll
        for (int k = 0; k < 3; ++k) jout[INVMAP[i] * 3 + k] = tc[k] + tv[k];

        writeATF(ATF, b, i, Rc, tc, Jrc[s]);
    }
}

// ---------------------------------------------------------------------------
// issue the 16KB fragment set of v-tile vt into LDS buffer dst (async,
// global_load_lds width 16): wave w stages chunks [4w, 4w+4), 1KB each.
// ---------------------------------------------------------------------------
__device__ __forceinline__ void stage_tile(
    const __hip_bfloat16* __restrict__ PtxF,
    const __hip_bfloat16* __restrict__ WF,
    int vt, short* dst, int wave, int lane)
{
#pragma unroll
    for (int c = 0; c < 4; ++c) {
        int g = wave * 4 + c;   // 0..15 (wave-uniform)
        const char* src = (g < 15)
            ? (const char*)PtxF + ((size_t)vt * 15 + g) * 1024
            : (const char*)WF + (size_t)vt * 1024;
        src += lane * 16;
        char* d = (char*)dst + g * 1024;   // wave-uniform base; HW adds lane*16
        __builtin_amdgcn_global_load_lds(
            (const __attribute__((address_space(1))) void*)src,
            (__attribute__((address_space(3))) void*)d,
            16, 0, 0);
    }
}

// ---------------------------------------------------------------------------
// Kernel C: all-MFMA verts kernel — triple-buffered async LDS pipeline with
// counted vmcnt (the empirical best, round 16 = 42.4 µs total).
// Iter i: issue stage(i+2) [pinned oldest], compute buf[i%3], then
// s_waitcnt vmcnt(8) + raw s_barrier. Accounting: every tile issues >=4
// unmergeable store instructions after the 4 stage loads, so the 8 newest
// outstanding ops are {S_i(>=4), L_{i+2}(4)}; waiting to <=8 provably
// retires L_{i+1} (needed next iter) with a full iteration of latency
// cover, while recent stores stay in flight (no drain).
// Dead tiles 49-51 removed: vg = [13,12,12,12] over tiles 0..48.
// ---------------------------------------------------------------------------
__global__ __launch_bounds__(256, 2) void verts_kernel(
    const __hip_bfloat16* __restrict__ pfx,
    const __hip_bfloat16* __restrict__ PtxF,
    const __hip_bfloat16* __restrict__ WF,
    const __hip_bfloat16* __restrict__ ATF,
    const float* __restrict__ tvec,
    float* __restrict__ out_verts, float* __restrict__ out_joints)
{
    __shared__ __align__(16) short Bs[3][16 * 64 * 8];   // 3 x 16 KB

    int tid = threadIdx.x;
    int lane = tid & 63;
    int wave = tid >> 6;
    int l15 = lane & 15;
    int lg  = lane >> 4;

    int bt = blockIdx.x * 4 + wave;   // wave-private batch tile, 0..511
    int b0 = bt * 16;
    int vg = blockIdx.y;              // 0..3

    int start = (vg == 0) ? 0 : 13 + (vg - 1) * 12;   // 0,13,25,37
    int count = (vg == 0) ? 13 : 12;                  // covers tiles 0..48

    // A-side operands, held for all v-tiles
    short8v hA[5];
#pragma unroll
    for (int kc = 0; kc < 5; ++kc)
        hA[kc] = *(const short8v*)(pfx + (size_t)(b0 + l15) * KEXT + kc * 32 + lg * 8);

    short8v tA[12];
#pragma unroll
    for (int mn = 0; mn < 12; ++mn)
        tA[mn] = *(const short8v*)(ATF + (((size_t)bt * 12 + mn) * 32 + (lane & 31)) * 8);

    float tv[4][3];
#pragma unroll
    for (int r = 0; r < 4; ++r) {
        int b = b0 + lg * 4 + r;
#pragma unroll
        for (int m = 0; m < 3; ++m) tv[r][m] = tvec[b * 3 + m];
    }

    // prologue: stage tiles 0 and 1; wait only for tile 0 (L_1 stays in flight)
    stage_tile(PtxF, WF, start, &Bs[0][0], wave, lane);
    if (count > 1)
        stage_tile(PtxF, WF, start + 1, &Bs[1][0], wave, lane);
    asm volatile("s_waitcnt vmcnt(4)" ::: "memory");
    __builtin_amdgcn_s_barrier();
    __builtin_amdgcn_sched_barrier(0);

    for (int i = 0; i < count; ++i) {
        int vt = start + i;
        const short* cur = &Bs[i % 3][0];

        // issue stage(i+2) FIRST (4 loads/wave, async), pinned oldest
        if (i + 2 < count)
            stage_tile(PtxF, WF, vt + 2, &Bs[(i + 2) % 3][0], wave, lane);
        __builtin_amdgcn_sched_barrier(0);

        // batched ds_read: all 16 fragments issued back-to-back
        short8v hB[15];
#pragma unroll
        for (int f = 0; f < 15; ++f)
            hB[f] = *(const short8v*)(cur + f * 512 + lane * 8);
        short8v wf = *(const short8v*)(cur + 15 * 512 + lane * 8);

        float4v hacc[3], Tacc[12];
#pragma unroll
        for (int k = 0; k < 3; ++k) hacc[k] = (float4v){0.f, 0.f, 0.f, 0.f};
#pragma unroll
        for (int mn = 0; mn < 12; ++mn) Tacc[mn] = (float4v){0.f, 0.f, 0.f, 0.f};

#pragma unroll
        for (int k = 0; k < 3; ++k)
#pragma unroll
            for (int kc = 0; kc < 5; ++kc)
                hacc[k] = __builtin_amdgcn_mfma_f32_16x16x32_bf16(
                    hA[kc], hB[k * 5 + kc], hacc[k], 0, 0, 0);

#pragma unroll
        for (int mn = 0; mn < 12; ++mn)
            Tacc[mn] = __builtin_amdgcn_mfma_f32_16x16x32_bf16(
                tA[mn], wf, Tacc[mn], 0, 0, 0);

        int v = vt * 16 + l15;
        int dest = (v == 745) ? 4 : (v == 333) ? 8 : (v == 444) ? 12 :
                   (v == 555) ? 16 : (v == 672) ? 20 : -1;

        if (v < NVERT) {
#pragma unroll
            for (int r = 0; r < 4; ++r) {
                float h0 = hacc[0][r], h1 = hacc[1][r], h2 = hacc[2][r];
                float e0 = Tacc[0][r] * h0 + Tacc[1][r] * h1 + Tacc[2][r]  * h2 + Tacc[3][r]  + tv[r][0];
                float e1 = Tacc[4][r] * h0 + Tacc[5][r] * h1 + Tacc[6][r]  * h2 + Tacc[7][r]  + tv[r][1];
                float e2 = Tacc[8][r] * h0 + Tacc[9][r] * h1 + Tacc[10][r] * h2 + Tacc[11][r] + tv[r][2];
                int b = b0 + lg * 4 + r;
                size_t idx = ((size_t)b * NVERT + v) * 3;
                out_verts[idx + 0] = e0;
                out_verts[idx + 1] = e1;
                out_verts[idx + 2] = e2;
                if (dest >= 0) {
                    size_t jidx = (size_t)b * 63 + dest * 3;
                    out_joints[jidx + 0] = e0;
                    out_joints[jidx + 1] = e1;
                    out_joints[jidx + 2] = e2;
                }
            }
        }

        // counted wait at depth 3: newest 8 outstanding = S_i(>=4)+L_{i+2}(4);
        // L_{i+1} (consumed next iter) and older are provably retired.
        if (i + 1 < count) {
            asm volatile("s_waitcnt vmcnt(8)" ::: "memory");
            __builtin_amdgcn_s_barrier();
            __builtin_amdgcn_sched_barrier(0);
        }
    }
}

extern "C" void kernel_launch(void* const* d_in, const int* in_sizes, int n_in,
                              void* d_out, int out_size, void* d_ws, size_t ws_size,
                              hipStream_t stream)
{
    const float* beta  = (const float*)d_in[0];
    const float* pose  = (const float*)d_in[1];
    const float* rvec  = (const float*)d_in[2];
    const float* tvec  = (const float*)d_in[3];
    const float* V     = (const float*)d_in[4];
    const float* S     = (const float*)d_in[5];
    const float* P     = (const float*)d_in[6];
    const float* J_reg = (const float*)d_in[7];
    const float* W     = (const float*)d_in[8];

    float* out    = (float*)d_out;
    float* verts  = out;
    float* joints = out + (size_t)BATCH * NVERT * 3;

    char* wsb = (char*)d_ws;
    float*          wsJS = (float*)(wsb + WSB_JS);
    __hip_bfloat16* pfx  = (__hip_bfloat16*)(wsb + WSB_PFX);
    __hip_bfloat16* PtxF = (__hip_bfloat16*)(wsb + WSB_PTXF);
    __hip_bfloat16* WFp  = (__hip_bfloat16*)(wsb + WSB_WF);
    __hip_bfloat16* ATF  = (__hip_bfloat16*)(wsb + WSB_ATF);

    hipLaunchKernelGGL(prep_kernel, dim3(340), dim3(256), 0, stream,
                       S, V, J_reg, P, W, wsJS, PtxF, WFp);
    hipLaunchKernelGGL(chain_kernel, dim3(160), dim3(256), 0, stream,
                       beta, pose, rvec, tvec, wsJS, pfx, ATF, joints);
    hipLaunchKernelGGL(verts_kernel, dim3(128, 4), dim3(256), 0, stream,
                       pfx, PtxF, WFp, ATF, tvec, verts, joints);
}